// Round 8
// baseline (219.603 us; speedup 1.0000x reference)
//
#include <hip/hip_runtime.h>
#include <hip/hip_bf16.h>

typedef __attribute__((ext_vector_type(8))) short bf16x8;
typedef __attribute__((ext_vector_type(4))) float f32x4;
typedef __attribute__((ext_vector_type(16))) float f32x16;
typedef unsigned short u16;
typedef unsigned int u32;

#define NUM_HEAD 16
#define HEAD_DIM 64
#define SEQ_N 2048
#define SEQ_K 2048
#define EMB 1024
#define MROWS 4096          // B*N == B*K
// HEAD_DIM^-0.5 * log2(e): Q pre-scaled so softmax uses raw v_exp_f32 (exp2)
static constexpr float ATTN_SCALE_LOG2E = 0.125f * 1.44269504f;

#if __has_builtin(__builtin_amdgcn_exp2f)
#define EXP2(x) __builtin_amdgcn_exp2f(x)
#else
#define EXP2(x) __expf(0.69314718056f * (x))
#endif

#if __has_builtin(__builtin_amdgcn_rcpf)
#define RCP(x) __builtin_amdgcn_rcpf(x)
#else
#define RCP(x) (1.0f / (x))
#endif

__device__ __forceinline__ u16 f2bf(float f) {
  __hip_bfloat16 h = __float2bfloat16(f);
  return *reinterpret_cast<u16*>(&h);
}

__device__ __forceinline__ u32 pack2(float lo, float hi) {
  __hip_bfloat162 h = __float22bfloat162_rn(make_float2(lo, hi));
  return *reinterpret_cast<u32*>(&h);
}

// v_permlane32_swap_b32: a' = [a.lo | b.lo], b' = [a.hi | b.hi]
__device__ __forceinline__ void plswap(u32& a, u32& b) {
  auto r = __builtin_amdgcn_permlane32_swap(a, b, false, false);
  a = r[0]; b = r[1];
}

// async global->LDS 16B copy; LDS dest is wave-uniform base + lane*16 —
// staging layouts below are linear in tid; swizzles via pre-swizzled SOURCE.
__device__ __forceinline__ void async16(const u16* g, u16* l) {
  __builtin_amdgcn_global_load_lds(
      (const __attribute__((address_space(1))) unsigned int*)g,
      (__attribute__((address_space(3))) unsigned int*)l, 16, 0, 0);
}

// ---- fused input-convert + weight-transpose (one dispatch, R8) ------------
__global__ __launch_bounds__(256) void cvt_all(
    const float* __restrict__ x, const float* __restrict__ ctx,
    const float* __restrict__ Wq, const float* __restrict__ Wkv,
    const float* __restrict__ Wproj,
    u16* __restrict__ xb, u16* __restrict__ cb,
    u16* __restrict__ Wqt, u16* __restrict__ Wkvt, u16* __restrict__ Wpt) {
  __shared__ float tile[32][33];
  const int bid = blockIdx.x;
  if (bid < 8192) {
    const int n4 = MROWS * EMB / 4;
    int gid = bid * 256 + threadIdx.x;
    const float4* s; ushort4* d; int i;
    if (gid < n4) { s = (const float4*)x;   d = (ushort4*)xb; i = gid; }
    else          { s = (const float4*)ctx; d = (ushort4*)cb; i = gid - n4; }
    float4 v = s[i];
    ushort4 o;
    o.x = f2bf(v.x); o.y = f2bf(v.y); o.z = f2bf(v.z); o.w = f2bf(v.w);
    d[i] = o;
    return;
  }
  const int tb = bid - 8192;            // 0..4095
  const int z = tb >> 10;
  const float* W; u16* Wt; int srcN, colbase;
  if (z == 0)      { W = Wq;    Wt = Wqt;                          srcN = 1024; colbase = 0; }
  else if (z == 1) { W = Wkv;   Wt = Wkvt;                         srcN = 2048; colbase = 0; }
  else if (z == 2) { W = Wkv;   Wt = Wkvt + (size_t)1024 * 1024;   srcN = 2048; colbase = 1024; }
  else             { W = Wproj; Wt = Wpt;                          srcN = 1024; colbase = 0; }
  int n0 = (tb & 31) * 32, k0 = ((tb >> 5) & 31) * 32;
  int tx = threadIdx.x & 31, ty = threadIdx.x >> 5;
  #pragma unroll
  for (int i = ty; i < 32; i += 8)
    tile[i][tx] = W[(size_t)(k0 + i) * srcN + colbase + n0 + tx];
  __syncthreads();
  #pragma unroll
  for (int i = ty; i < 32; i += 8)
    Wt[(size_t)(n0 + i) * 1024 + k0 + tx] = f2bf(tile[tx][i]);
}

// ---------- fused Q + KV projection GEMM: m97-structure 128x128 (R5) -------
__global__ __launch_bounds__(256, 3) void gemm_qkv(
    const u16* __restrict__ xb, const u16* __restrict__ cb,
    const u16* __restrict__ Wqt, const u16* __restrict__ Wkvt,
    const float* __restrict__ bq, const float* __restrict__ bkv,
    u16* __restrict__ Qb, u16* __restrict__ Kb, u16* __restrict__ Vtb)
{
  __shared__ alignas(16) u16 smem[(128 + 128) * 64];
  u16* As = smem;                   // 128 x 64
  u16* Bs = smem + 128 * 64;        // 128 x 64
  const int tid = threadIdx.x;
  const bool isQ = (blockIdx.y < 8);
  const int n0 = (isQ ? blockIdx.y : blockIdx.y - 8) * 128;
  const int m0 = blockIdx.x * 128;
  const u16* A      = isQ ? xb : cb;
  const u16* Wt     = isQ ? Wqt : Wkvt;
  const float* bias = isQ ? bq : bkv;
  const int wave = tid >> 6, lane = tid & 63;
  const int wm = (wave >> 1) * 64, wn = (wave & 1) * 64;
  const int l15 = lane & 15, quad = lane >> 4;

  f32x4 acc[4][4];
  #pragma unroll
  for (int i = 0; i < 4; i++)
    #pragma unroll
    for (int j = 0; j < 4; j++)
      #pragma unroll
      for (int r = 0; r < 4; r++) acc[i][j][r] = 0.0f;

  const int srow = tid >> 3;          // 0..31
  const int scol = (tid & 7) * 8;     // u16 col
  const u16* ag = A + (size_t)(m0 + srow) * EMB + scol;
  const u16* bg = Wt + (size_t)(n0 + srow) * EMB + scol;
  const int ldsoff = tid * 8;

  for (int kt = 0; kt < EMB; kt += 64) {
    #pragma unroll
    for (int s = 0; s < 4; s++) {
      async16(ag + (size_t)(s * 32) * EMB + kt, &As[ldsoff + s * 2048]);
      async16(bg + (size_t)(s * 32) * EMB + kt, &Bs[ldsoff + s * 2048]);
    }
    __syncthreads();
    #pragma unroll
    for (int ks = 0; ks < 2; ks++) {
      bf16x8 af[4], bfr[4];
      #pragma unroll
      for (int i = 0; i < 4; i++)
        af[i]  = *(const bf16x8*)&As[(wm + i * 16 + l15) * 64 + ks * 32 + quad * 8];
      #pragma unroll
      for (int j = 0; j < 4; j++)
        bfr[j] = *(const bf16x8*)&Bs[(wn + j * 16 + l15) * 64 + ks * 32 + quad * 8];
      #pragma unroll
      for (int i = 0; i < 4; i++)
        #pragma unroll
        for (int j = 0; j < 4; j++)
          acc[i][j] = __builtin_amdgcn_mfma_f32_16x16x32_bf16(af[i], bfr[j], acc[i][j], 0, 0, 0);
    }
    __syncthreads();
  }

  const int h = ((n0 + wn) >> 6) & 15;      // wave-uniform head
  if (isQ) {
    #pragma unroll
    for (int j = 0; j < 4; j++) {
      const int gc = n0 + wn + j * 16 + l15;
      const float bv = bias[gc];
      const int d = j * 16 + l15;
      #pragma unroll
      for (int i = 0; i < 4; i++) {
        #pragma unroll
        for (int r = 0; r < 4; r++) {
          const int gm = m0 + wm + i * 16 + quad * 4 + r;
          const int bb = gm >> 11, nn = gm & 2047;
          Qb[((size_t)(bb * NUM_HEAD + h) * SEQ_N + nn) * HEAD_DIM + d] =
              f2bf((acc[i][j][r] + bv) * ATTN_SCALE_LOG2E);
        }
      }
    }
  } else if ((n0 >> 10) == 0) {  // K half -> [B,H,K,hd]
    #pragma unroll
    for (int j = 0; j < 4; j++) {
      const int gc = n0 + wn + j * 16 + l15;
      const float bv = bias[gc];
      const int d = j * 16 + l15;
      #pragma unroll
      for (int i = 0; i < 4; i++) {
        #pragma unroll
        for (int r = 0; r < 4; r++) {
          const int gm = m0 + wm + i * 16 + quad * 4 + r;
          const int bb = gm >> 11, kk = gm & 2047;
          Kb[((size_t)(bb * NUM_HEAD + h) * SEQ_K + kk) * HEAD_DIM + d] =
              f2bf(acc[i][j][r] + bv);
        }
      }
    }
  } else {  // V half -> [B,H,hd,K], barrier-free per-wave LDS transpose
    u16* wbuf = smem + wave * 1088;     // 16 x 68 u16, wave-private
    const int gm0 = m0 + wm;
    const int bb = gm0 >> 11;
    const int kk0 = gm0 & 2047;
    #pragma unroll
    for (int j = 0; j < 4; j++) {
      const int gc = n0 + wn + j * 16 + l15;
      const float bv = bias[gc];
      #pragma unroll
      for (int i = 0; i < 4; i++) {
        ushort4 pk;
        pk.x = f2bf(acc[i][j][0] + bv);
        pk.y = f2bf(acc[i][j][1] + bv);
        pk.z = f2bf(acc[i][j][2] + bv);
        pk.w = f2bf(acc[i][j][3] + bv);
        *(ushort4*)&wbuf[l15 * 68 + i * 16 + quad * 4] = pk;
      }
      #pragma unroll
      for (int it = 0; it < 2; it++) {
        const int dd = it * 8 + (lane >> 3);
        const int kp = (lane & 7) * 8;
        uint4 v = *(const uint4*)&wbuf[dd * 68 + kp];
        *(uint4*)(Vtb + ((size_t)(bb * NUM_HEAD + h) * HEAD_DIM + j * 16 + dd) * SEQ_K
                  + kk0 + kp) = v;
      }
    }
  }
}

// ------ out-projection GEMM (fused split-K combine, R8): 64x128 tile -------
// A[row][col] = (Oa+Ob) * rcp(la+lb) -> bf16 -> ds_write (reg-staged A;
// B stays global_load_lds).  col's head hh = kt/64 is K-tile-uniform.
__global__ __launch_bounds__(256) void gemm_proj(
    const float* __restrict__ Oa, const float* __restrict__ Obp,
    const float* __restrict__ Da, const float* __restrict__ Dbp,
    const u16* __restrict__ Wt,
    const float* __restrict__ bias, float* __restrict__ outF)
{
  __shared__ alignas(16) u16 smem[(64 + 128) * 64];
  u16* As = smem;                 // 64 x 64
  u16* Bs = smem + 64 * 64;       // 128 x 64
  const int tid = threadIdx.x;
  const int n0 = blockIdx.y * 128, m0 = blockIdx.x * 64;
  const int wave = tid >> 6, lane = tid & 63;
  const int wm = (wave >> 1) * 32, wn = (wave & 1) * 64;
  const int l15 = lane & 15, quad = lane >> 4;

  f32x4 acc[2][4];
  #pragma unroll
  for (int i = 0; i < 2; i++)
    #pragma unroll
    for (int j = 0; j < 4; j++)
      #pragma unroll
      for (int r = 0; r < 4; r++) acc[i][j][r] = 0.0f;

  const int srow = tid >> 3;          // 0..31
  const int scol = (tid & 7) * 8;     // element col within 64-wide K-tile
  const u16* bg = Wt + (size_t)(n0 + srow) * EMB + scol;
  const int ldsoff = tid * 8;

  for (int kt = 0; kt < EMB; kt += 64) {
    #pragma unroll
    for (int s = 0; s < 4; s++)
      async16(bg + (size_t)(s * 32) * EMB + kt, &Bs[ldsoff + s * 2048]);
    const int hh = kt >> 6;
    #pragma unroll
    for (int s = 0; s < 2; s++) {
      const int grow = m0 + srow + s * 32;
      const float inv = RCP(Da[grow * 16 + hh] + Dbp[grow * 16 + hh]);
      const float4 a0 = *(const float4*)&Oa [(size_t)grow * EMB + kt + scol];
      const float4 a1 = *(const float4*)&Oa [(size_t)grow * EMB + kt + scol + 4];
      const float4 b0 = *(const float4*)&Obp[(size_t)grow * EMB + kt + scol];
      const float4 b1 = *(const float4*)&Obp[(size_t)grow * EMB + kt + scol + 4];
      ushort4 p0, p1;
      p0.x = f2bf((a0.x + b0.x) * inv); p0.y = f2bf((a0.y + b0.y) * inv);
      p0.z = f2bf((a0.z + b0.z) * inv); p0.w = f2bf((a0.w + b0.w) * inv);
      p1.x = f2bf((a1.x + b1.x) * inv); p1.y = f2bf((a1.y + b1.y) * inv);
      p1.z = f2bf((a1.z + b1.z) * inv); p1.w = f2bf((a1.w + b1.w) * inv);
      *(ushort4*)&As[ldsoff + s * 2048]     = p0;
      *(ushort4*)&As[ldsoff + s * 2048 + 4] = p1;
    }
    __syncthreads();
    #pragma unroll
    for (int ks = 0; ks < 2; ks++) {
      bf16x8 af[2], bfr[4];
      #pragma unroll
      for (int i = 0; i < 2; i++)
        af[i]  = *(const bf16x8*)&As[(wm + i * 16 + l15) * 64 + ks * 32 + quad * 8];
      #pragma unroll
      for (int j = 0; j < 4; j++)
        bfr[j] = *(const bf16x8*)&Bs[(wn + j * 16 + l15) * 64 + ks * 32 + quad * 8];
      #pragma unroll
      for (int i = 0; i < 2; i++)
        #pragma unroll
        for (int j = 0; j < 4; j++)
          acc[i][j] = __builtin_amdgcn_mfma_f32_16x16x32_bf16(af[i], bfr[j], acc[i][j], 0, 0, 0);
    }
    __syncthreads();
  }

  #pragma unroll
  for (int i = 0; i < 2; i++) {
    #pragma unroll
    for (int j = 0; j < 4; j++) {
      const int gc = n0 + wn + j * 16 + l15;
      const float bv = bias[gc];
      #pragma unroll
      for (int r = 0; r < 4; r++) {
        const int gm = m0 + wm + i * 16 + quad * 4 + r;
        outF[(size_t)gm * EMB + gc] = acc[i][j][r] + bv;
      }
    }
  }
}

// -------- flash attention, split-K (R8): swapped-QK^T 32x32, P in regs --------
// TLP was capped at 2 waves/SIMD (2048 waves total) — time invariant 51.6us
// across 4 instruction-stream variants (R4-R7).  Split-K: grid (32 bh,
// 16 mb, 2 kh) = 1024 blocks, KT=64, LDS 32KB dbuf -> 4 blocks/CU = 4
// waves/SIMD.  Partials additive (no max-subtraction): unnormalized fp32 O
// + per-(row,head) denominators; combine fused into gemm_proj.
__global__ __launch_bounds__(256, 4) void attn_kernel(
    const u16* __restrict__ Qb, const u16* __restrict__ Kb,
    const u16* __restrict__ Vtb,
    float* __restrict__ Op0, float* __restrict__ Op1, float* __restrict__ Dp0)
{
  __shared__ alignas(16) u16 Ks[2][64 * 64];   // [key][d], pitch 128B, 3-bit swz
  __shared__ alignas(16) u16 Vs[2][64 * 64];   // [d][key], pitch 128B, 3-bit swz
  const int tid = threadIdx.x;
  const int bh = blockIdx.x;
  const int m0 = blockIdx.y * 128;
  const int kh = blockIdx.z;
  const int kbase = kh << 10;
  float* Op = kh ? Op1 : Op0;
  float* Dp = Dp0 + (size_t)kh * MROWS * NUM_HEAD;
  const int wave = tid >> 6, lane = tid & 63;
  const int l31 = lane & 31, hi = lane >> 5;
  const int hi16 = hi * 16;
  const int swz = (l31 & 7) << 4;
  const int rowb = m0 + wave * 32;

  bf16x8 bq[4];
  {
    const u16* qp = Qb + ((size_t)bh * SEQ_N + rowb + l31) * HEAD_DIM + hi * 8;
    #pragma unroll
    for (int db = 0; db < 4; db++) bq[db] = *(const bf16x8*)(qp + db * 16);
  }

  f32x16 o0, o1, od;
  #pragma unroll
  for (int r = 0; r < 16; r++) { o0[r] = 0.f; o1[r] = 0.f; od[r] = 0.f; }
  f32x16 zc;
  #pragma unroll
  for (int r = 0; r < 16; r++) zc[r] = 0.f;
  union { u32 u[4]; bf16x8 v; } ones;
  ones.u[0] = ones.u[1] = ones.u[2] = ones.u[3] = 0x3F803F80u;

  const int srow = tid >> 3;                       // 0..31
  const int sgx  = (tid & 7) ^ (srow & 7);         // pre-swizzled src granule
  const u16* kg = Kb  + (size_t)bh * SEQ_K * HEAD_DIM;   // [k][d]
  const u16* vg = Vtb + (size_t)bh * HEAD_DIM * SEQ_K;   // [d][k]

#define STAGE(kt_, nb_) do {                                                   \
    _Pragma("unroll")                                                          \
    for (int s = 0; s < 2; s++) {                                              \
      async16(kg + (size_t)((kt_) + s * 32 + srow) * HEAD_DIM + sgx * 8,       \
              &Ks[nb_][s * 2048 + tid * 8]);                                   \
      async16(vg + (size_t)(s * 32 + srow) * SEQ_K + (kt_) + sgx * 8,          \
              &Vs[nb_][s * 2048 + tid * 8]);                                   \
    }                                                                          \
  } while (0)

  STAGE(kbase, 0);
  __syncthreads();

  for (int kt = 0; kt < 1024; kt += 64) {
    const int cur = (kt >> 6) & 1;
    if (kt + 64 < 1024) STAGE(kbase + kt + 64, cur ^ 1);
    const char* KsB = (const char*)Ks[cur];
    const char* VsB = (const char*)Vs[cur];

    #pragma unroll
    for (int g = 0; g < 2; g++) {
      __builtin_amdgcn_s_setprio(1);
      bf16x8 ka = *(const bf16x8*)(KsB + (g * 32 + l31) * 128 + (hi16 ^ swz));
      f32x16 s = __builtin_amdgcn_mfma_f32_32x32x16_bf16(ka, bq[0], zc, 0, 0, 0);
      #pragma unroll
      for (int db = 1; db < 4; db++) {
        ka = *(const bf16x8*)(KsB + (g * 32 + l31) * 128 + ((db * 32 + hi16) ^ swz));
        s = __builtin_amdgcn_mfma_f32_32x32x16_bf16(ka, bq[db], s, 0, 0, 0);
      }
      __builtin_amdgcn_s_setprio(0);

      float p[16];
      #pragma unroll
      for (int r = 0; r < 16; r++) p[r] = EXP2(s[r]);
      u32 w0 = pack2(p[0],  p[1]),  w1 = pack2(p[2],  p[3]);
      u32 w2 = pack2(p[4],  p[5]),  w3 = pack2(p[6],  p[7]);
      u32 w4 = pack2(p[8],  p[9]),  w5 = pack2(p[10], p[11]);
      u32 w6 = pack2(p[12], p[13]), w7 = pack2(p[14], p[15]);
      plswap(w0, w2); plswap(w1, w3);
      plswap(w4, w6); plswap(w5, w7);
      union PU { u32 u[4]; bf16x8 v; } pa0, pa1;
      pa0.u[0] = w0; pa0.u[1] = w1; pa0.u[2] = w2; pa0.u[3] = w3;
      pa1.u[0] = w4; pa1.u[1] = w5; pa1.u[2] = w6; pa1.u[3] = w7;

      __builtin_amdgcn_s_setprio(1);
      bf16x8 vb00 = *(const bf16x8*)(VsB + (l31)*128      + ((g * 64 + hi16)      ^ swz));
      bf16x8 vb01 = *(const bf16x8*)(VsB + (l31)*128      + ((g * 64 + 32 + hi16) ^ swz));
      bf16x8 vb10 = *(const bf16x8*)(VsB + (32 + l31)*128 + ((g * 64 + hi16)      ^ swz));
      bf16x8 vb11 = *(const bf16x8*)(VsB + (32 + l31)*128 + ((g * 64 + 32 + hi16) ^ swz));
      o0 = __builtin_amdgcn_mfma_f32_32x32x16_bf16(pa0.v, vb00, o0, 0, 0, 0);
      o1 = __builtin_amdgcn_mfma_f32_32x32x16_bf16(pa0.v, vb10, o1, 0, 0, 0);
      od = __builtin_amdgcn_mfma_f32_32x32x16_bf16(pa0.v, ones.v, od, 0, 0, 0);
      o0 = __builtin_amdgcn_mfma_f32_32x32x16_bf16(pa1.v, vb01, o0, 0, 0, 0);
      o1 = __builtin_amdgcn_mfma_f32_32x32x16_bf16(pa1.v, vb11, o1, 0, 0, 0);
      od = __builtin_amdgcn_mfma_f32_32x32x16_bf16(pa1.v, ones.v, od, 0, 0, 0);
      __builtin_amdgcn_s_setprio(0);
    }
    __syncthreads();
  }
#undef STAGE

  const int bb = bh >> 4, hh = bh & 15;
  #pragma unroll
  for (int r = 0; r < 16; r++) {
    const int qrow = (r & 3) + 8 * (r >> 2) + 4 * hi;
    const size_t grow = (size_t)bb * SEQ_N + (rowb + qrow);
    float* op = Op + grow * EMB + hh * HEAD_DIM + l31;
    op[0]  = o0[r];
    op[32] = o1[r];
    if (l31 == 0) Dp[grow * 16 + hh] = od[r];   // all cols of od equal
  }
}

extern "C" void kernel_launch(void* const* d_in, const int* in_sizes, int n_in,
                              void* d_out, int out_size, void* d_ws, size_t ws_size,
                              hipStream_t stream)
{
  const float* x     = (const float*)d_in[0];
  const float* ctx   = (const float*)d_in[1];
  const float* Wq    = (const float*)d_in[2];
  const float* bq    = (const float*)d_in[3];
  const float* Wkv   = (const float*)d_in[4];
  const float* bkv   = (const float*)d_in[5];
  const float* Wproj = (const float*)d_in[6];
  const float* bproj = (const float*)d_in[7];
  float* out = (float*)d_out;

  char* ws = (char*)d_ws;
  size_t off = 0;
  auto walloc = [&](size_t bytes) -> void* {
    void* p = ws + off;
    off += (bytes + 255) & ~(size_t)255;
    return p;
  };
  u16* xb   = (u16*)walloc((size_t)MROWS * EMB * 2);
  u16* cb   = (u16*)walloc((size_t)MROWS * EMB * 2);
  u16* Wqt  = (u16*)walloc((size_t)EMB * EMB * 2);
  u16* Wkvt = (u16*)walloc((size_t)2 * EMB * EMB * 2);
  u16* Wpt  = (u16*)walloc((size_t)EMB * EMB * 2);
  u16* Qb   = (u16*)walloc((size_t)MROWS * EMB * 2);
  u16* Kb   = (u16*)walloc((size_t)MROWS * EMB * 2);
  u16* Vtb  = (u16*)walloc((size_t)MROWS * EMB * 2);
  // split-K partials: Opart0 aliases xb+cb (16MB, dead after gemm_qkv)
  float* Opart0 = (float*)xb;
  float* Opart1 = (float*)walloc((size_t)MROWS * EMB * 4);
  float* Dpart  = (float*)walloc((size_t)2 * MROWS * NUM_HEAD * 4);
  float* Dpart1 = Dpart + (size_t)MROWS * NUM_HEAD;

  cvt_all<<<12288, 256, 0, stream>>>(x, ctx, Wq, Wkv, Wproj, xb, cb, Wqt, Wkvt, Wpt);
  gemm_qkv<<<dim3(32, 24), 256, 0, stream>>>(xb, cb, Wqt, Wkvt, bq, bkv, Qb, Kb, Vtb);
  attn_kernel<<<dim3(32, 16, 2), 256, 0, stream>>>(Qb, Kb, Vtb, Opart0, Opart1, Dpart);
  gemm_proj<<<dim3(64, 8), 256, 0, stream>>>(Opart0, Opart1, Dpart, Dpart1,
                                             Wpt, bproj, out);
}

// Round 9
// 202.100 us; speedup vs baseline: 1.0866x; 1.0866x over previous
//
#include <hip/hip_runtime.h>
#include <hip/hip_bf16.h>

typedef __attribute__((ext_vector_type(8))) short bf16x8;
typedef __attribute__((ext_vector_type(4))) float f32x4;
typedef __attribute__((ext_vector_type(16))) float f32x16;
typedef unsigned short u16;
typedef unsigned int u32;

#define NUM_HEAD 16
#define HEAD_DIM 64
#define SEQ_N 2048
#define SEQ_K 2048
#define EMB 1024
#define MROWS 4096          // B*N == B*K
// HEAD_DIM^-0.5 * log2(e): Q pre-scaled so softmax uses raw v_exp_f32 (exp2)
static constexpr float ATTN_SCALE_LOG2E = 0.125f * 1.44269504f;

#if __has_builtin(__builtin_amdgcn_exp2f)
#define EXP2(x) __builtin_amdgcn_exp2f(x)
#else
#define EXP2(x) __expf(0.69314718056f * (x))
#endif

#if __has_builtin(__builtin_amdgcn_rcpf)
#define RCP(x) __builtin_amdgcn_rcpf(x)
#else
#define RCP(x) (1.0f / (x))
#endif

__device__ __forceinline__ u16 f2bf(float f) {
  __hip_bfloat16 h = __float2bfloat16(f);
  return *reinterpret_cast<u16*>(&h);
}

__device__ __forceinline__ u32 pack2(float lo, float hi) {
  __hip_bfloat162 h = __float22bfloat162_rn(make_float2(lo, hi));
  return *reinterpret_cast<u32*>(&h);
}

// v_permlane32_swap_b32: a' = [a.lo | b.lo], b' = [a.hi | b.hi]
__device__ __forceinline__ void plswap(u32& a, u32& b) {
  auto r = __builtin_amdgcn_permlane32_swap(a, b, false, false);
  a = r[0]; b = r[1];
}

// async global->LDS 16B copy; LDS dest is wave-uniform base + lane*16 —
// staging layouts below are linear in tid; swizzles via pre-swizzled SOURCE.
__device__ __forceinline__ void async16(const u16* g, u16* l) {
  __builtin_amdgcn_global_load_lds(
      (const __attribute__((address_space(1))) unsigned int*)g,
      (__attribute__((address_space(3))) unsigned int*)l, 16, 0, 0);
}

// ---- fused input-convert + weight-transpose (one dispatch, R8) ------------
__global__ __launch_bounds__(256) void cvt_all(
    const float* __restrict__ x, const float* __restrict__ ctx,
    const float* __restrict__ Wq, const float* __restrict__ Wkv,
    const float* __restrict__ Wproj,
    u16* __restrict__ xb, u16* __restrict__ cb,
    u16* __restrict__ Wqt, u16* __restrict__ Wkvt, u16* __restrict__ Wpt) {
  __shared__ float tile[32][33];
  const int bid = blockIdx.x;
  if (bid < 8192) {
    const int n4 = MROWS * EMB / 4;
    int gid = bid * 256 + threadIdx.x;
    const float4* s; ushort4* d; int i;
    if (gid < n4) { s = (const float4*)x;   d = (ushort4*)xb; i = gid; }
    else          { s = (const float4*)ctx; d = (ushort4*)cb; i = gid - n4; }
    float4 v = s[i];
    ushort4 o;
    o.x = f2bf(v.x); o.y = f2bf(v.y); o.z = f2bf(v.z); o.w = f2bf(v.w);
    d[i] = o;
    return;
  }
  const int tb = bid - 8192;            // 0..4095
  const int z = tb >> 10;
  const float* W; u16* Wt; int srcN, colbase;
  if (z == 0)      { W = Wq;    Wt = Wqt;                          srcN = 1024; colbase = 0; }
  else if (z == 1) { W = Wkv;   Wt = Wkvt;                         srcN = 2048; colbase = 0; }
  else if (z == 2) { W = Wkv;   Wt = Wkvt + (size_t)1024 * 1024;   srcN = 2048; colbase = 1024; }
  else             { W = Wproj; Wt = Wpt;                          srcN = 1024; colbase = 0; }
  int n0 = (tb & 31) * 32, k0 = ((tb >> 5) & 31) * 32;
  int tx = threadIdx.x & 31, ty = threadIdx.x >> 5;
  #pragma unroll
  for (int i = ty; i < 32; i += 8)
    tile[i][tx] = W[(size_t)(k0 + i) * srcN + colbase + n0 + tx];
  __syncthreads();
  #pragma unroll
  for (int i = ty; i < 32; i += 8)
    Wt[(size_t)(n0 + i) * 1024 + k0 + tx] = f2bf(tile[tx][i]);
}

// ---------- fused Q + KV projection GEMM: m97-structure 128x128 (R5) -------
// 128x128 tile, BK=64, 4 waves of 64x64 (0.5 ds_read_b128/MFMA),
// global_load_lds w=16, 3 blocks/CU (LDS 32KB).  grid (32 mb FAST, 24 nb
// SLOW): consecutive blocks share one 256KB B-panel (L2-resident per XCD).
// nb<8: Q.  nb>=8: KV (K->[B,H,K,hd]; V->[B,H,hd,K] barrier-free wave T).
__global__ __launch_bounds__(256, 3) void gemm_qkv(
    const u16* __restrict__ xb, const u16* __restrict__ cb,
    const u16* __restrict__ Wqt, const u16* __restrict__ Wkvt,
    const float* __restrict__ bq, const float* __restrict__ bkv,
    u16* __restrict__ Qb, u16* __restrict__ Kb, u16* __restrict__ Vtb)
{
  __shared__ alignas(16) u16 smem[(128 + 128) * 64];
  u16* As = smem;                   // 128 x 64
  u16* Bs = smem + 128 * 64;        // 128 x 64
  const int tid = threadIdx.x;
  const bool isQ = (blockIdx.y < 8);
  const int n0 = (isQ ? blockIdx.y : blockIdx.y - 8) * 128;
  const int m0 = blockIdx.x * 128;
  const u16* A      = isQ ? xb : cb;
  const u16* Wt     = isQ ? Wqt : Wkvt;
  const float* bias = isQ ? bq : bkv;
  const int wave = tid >> 6, lane = tid & 63;
  const int wm = (wave >> 1) * 64, wn = (wave & 1) * 64;
  const int l15 = lane & 15, quad = lane >> 4;

  f32x4 acc[4][4];
  #pragma unroll
  for (int i = 0; i < 4; i++)
    #pragma unroll
    for (int j = 0; j < 4; j++)
      #pragma unroll
      for (int r = 0; r < 4; r++) acc[i][j][r] = 0.0f;

  const int srow = tid >> 3;          // 0..31
  const int scol = (tid & 7) * 8;     // u16 col
  const u16* ag = A + (size_t)(m0 + srow) * EMB + scol;
  const u16* bg = Wt + (size_t)(n0 + srow) * EMB + scol;
  const int ldsoff = tid * 8;

  for (int kt = 0; kt < EMB; kt += 64) {
    #pragma unroll
    for (int s = 0; s < 4; s++) {
      async16(ag + (size_t)(s * 32) * EMB + kt, &As[ldsoff + s * 2048]);
      async16(bg + (size_t)(s * 32) * EMB + kt, &Bs[ldsoff + s * 2048]);
    }
    __syncthreads();
    #pragma unroll
    for (int ks = 0; ks < 2; ks++) {
      bf16x8 af[4], bfr[4];
      #pragma unroll
      for (int i = 0; i < 4; i++)
        af[i]  = *(const bf16x8*)&As[(wm + i * 16 + l15) * 64 + ks * 32 + quad * 8];
      #pragma unroll
      for (int j = 0; j < 4; j++)
        bfr[j] = *(const bf16x8*)&Bs[(wn + j * 16 + l15) * 64 + ks * 32 + quad * 8];
      #pragma unroll
      for (int i = 0; i < 4; i++)
        #pragma unroll
        for (int j = 0; j < 4; j++)
          acc[i][j] = __builtin_amdgcn_mfma_f32_16x16x32_bf16(af[i], bfr[j], acc[i][j], 0, 0, 0);
    }
    __syncthreads();
  }

  const int h = ((n0 + wn) >> 6) & 15;      // wave-uniform head
  if (isQ) {
    #pragma unroll
    for (int j = 0; j < 4; j++) {
      const int gc = n0 + wn + j * 16 + l15;
      const float bv = bias[gc];
      const int d = j * 16 + l15;
      #pragma unroll
      for (int i = 0; i < 4; i++) {
        #pragma unroll
        for (int r = 0; r < 4; r++) {
          const int gm = m0 + wm + i * 16 + quad * 4 + r;
          const int bb = gm >> 11, nn = gm & 2047;
          Qb[((size_t)(bb * NUM_HEAD + h) * SEQ_N + nn) * HEAD_DIM + d] =
              f2bf((acc[i][j][r] + bv) * ATTN_SCALE_LOG2E);
        }
      }
    }
  } else if ((n0 >> 10) == 0) {  // K half -> [B,H,K,hd]
    #pragma unroll
    for (int j = 0; j < 4; j++) {
      const int gc = n0 + wn + j * 16 + l15;
      const float bv = bias[gc];
      const int d = j * 16 + l15;
      #pragma unroll
      for (int i = 0; i < 4; i++) {
        #pragma unroll
        for (int r = 0; r < 4; r++) {
          const int gm = m0 + wm + i * 16 + quad * 4 + r;
          const int bb = gm >> 11, kk = gm & 2047;
          Kb[((size_t)(bb * NUM_HEAD + h) * SEQ_K + kk) * HEAD_DIM + d] =
              f2bf(acc[i][j][r] + bv);
        }
      }
    }
  } else {  // V half -> [B,H,hd,K], barrier-free per-wave LDS transpose
    u16* wbuf = smem + wave * 1088;     // 16 x 68 u16, wave-private
    const int gm0 = m0 + wm;
    const int bb = gm0 >> 11;
    const int kk0 = gm0 & 2047;
    #pragma unroll
    for (int j = 0; j < 4; j++) {
      const int gc = n0 + wn + j * 16 + l15;
      const float bv = bias[gc];
      #pragma unroll
      for (int i = 0; i < 4; i++) {
        ushort4 pk;
        pk.x = f2bf(acc[i][j][0] + bv);
        pk.y = f2bf(acc[i][j][1] + bv);
        pk.z = f2bf(acc[i][j][2] + bv);
        pk.w = f2bf(acc[i][j][3] + bv);
        *(ushort4*)&wbuf[l15 * 68 + i * 16 + quad * 4] = pk;
      }
      #pragma unroll
      for (int it = 0; it < 2; it++) {
        const int dd = it * 8 + (lane >> 3);
        const int kp = (lane & 7) * 8;
        uint4 v = *(const uint4*)&wbuf[dd * 68 + kp];
        *(uint4*)(Vtb + ((size_t)(bb * NUM_HEAD + h) * HEAD_DIM + j * 16 + dd) * SEQ_K
                  + kk0 + kp) = v;
      }
    }
  }
}

// ---------- out-projection GEMM: m97-structure 128x128 (R9) ----------------
// Same proven structure as gemm_qkv: 128x128 tile, BK=64, 4 waves of 64x64
// (0.5 ds_read_b128/MFMA vs the old 64x128's 0.75), global_load_lds w=16,
// 3 blocks/CU.  grid (32 mb FAST, 8 nb SLOW).  Simple fp32 epilogue.
__global__ __launch_bounds__(256, 3) void gemm_proj(
    const u16* __restrict__ A, const u16* __restrict__ Wt,
    const float* __restrict__ bias, float* __restrict__ outF)
{
  __shared__ alignas(16) u16 smem[(128 + 128) * 64];
  u16* As = smem;                   // 128 x 64
  u16* Bs = smem + 128 * 64;        // 128 x 64
  const int tid = threadIdx.x;
  const int n0 = blockIdx.y * 128, m0 = blockIdx.x * 128;
  const int wave = tid >> 6, lane = tid & 63;
  const int wm = (wave >> 1) * 64, wn = (wave & 1) * 64;
  const int l15 = lane & 15, quad = lane >> 4;

  f32x4 acc[4][4];
  #pragma unroll
  for (int i = 0; i < 4; i++)
    #pragma unroll
    for (int j = 0; j < 4; j++)
      #pragma unroll
      for (int r = 0; r < 4; r++) acc[i][j][r] = 0.0f;

  const int srow = tid >> 3;          // 0..31
  const int scol = (tid & 7) * 8;     // u16 col
  const u16* ag = A + (size_t)(m0 + srow) * EMB + scol;
  const u16* bg = Wt + (size_t)(n0 + srow) * EMB + scol;
  const int ldsoff = tid * 8;

  for (int kt = 0; kt < EMB; kt += 64) {
    #pragma unroll
    for (int s = 0; s < 4; s++) {
      async16(ag + (size_t)(s * 32) * EMB + kt, &As[ldsoff + s * 2048]);
      async16(bg + (size_t)(s * 32) * EMB + kt, &Bs[ldsoff + s * 2048]);
    }
    __syncthreads();
    #pragma unroll
    for (int ks = 0; ks < 2; ks++) {
      bf16x8 af[4], bfr[4];
      #pragma unroll
      for (int i = 0; i < 4; i++)
        af[i]  = *(const bf16x8*)&As[(wm + i * 16 + l15) * 64 + ks * 32 + quad * 8];
      #pragma unroll
      for (int j = 0; j < 4; j++)
        bfr[j] = *(const bf16x8*)&Bs[(wn + j * 16 + l15) * 64 + ks * 32 + quad * 8];
      #pragma unroll
      for (int i = 0; i < 4; i++)
        #pragma unroll
        for (int j = 0; j < 4; j++)
          acc[i][j] = __builtin_amdgcn_mfma_f32_16x16x32_bf16(af[i], bfr[j], acc[i][j], 0, 0, 0);
    }
    __syncthreads();
  }

  #pragma unroll
  for (int j = 0; j < 4; j++) {
    const int gc = n0 + wn + j * 16 + l15;
    const float bv = bias[gc];
    #pragma unroll
    for (int i = 0; i < 4; i++) {
      #pragma unroll
      for (int r = 0; r < 4; r++) {
        const int gm = m0 + wm + i * 16 + quad * 4 + r;
        outF[(size_t)gm * EMB + gc] = acc[i][j][r] + bv;
      }
    }
  }
}

// ------------- flash attention (R6 form, reverted from split-K) ----------------
// 4 waves x 32 q-rows, grid (32 bh, 16) = 2 blocks/CU, KT=128 (16 barriers),
// DMA-staged dbuf K/V, both-sides XOR swizzle, swapped-QK^T 32x32, P in regs,
// zero-C hoist, ones-column MFMA denominator, bf16 output.  51.6-51.8us
// measured (R6/R7); plateau confirmed across 5 structural variants (R4-R8).
__global__ __launch_bounds__(256, 2) void attn_kernel(
    const u16* __restrict__ Qb, const u16* __restrict__ Kb,
    const u16* __restrict__ Vtb, u16* __restrict__ Ob)
{
  __shared__ alignas(16) u16 Ks[2][128 * 64];   // [key][d], pitch 128B, 3-bit swz
  __shared__ alignas(16) u16 Vs[2][64 * 128];   // [d][key], pitch 256B, 4-bit swz
  const int tid = threadIdx.x;
  const int bh = blockIdx.x;
  const int m0 = blockIdx.y * 128;
  const int wave = tid >> 6, lane = tid & 63;
  const int l31 = lane & 31, hi = lane >> 5;
  const int hi16 = hi * 16;
  const int swzK = (l31 & 7) << 4;        // K read-side XOR (row&7 == l31&7)
  const int swzV = (l31 & 15) << 4;       // V read-side XOR (d&15 == l31&15)
  const int rowb = m0 + wave * 32;

  bf16x8 bq[4];
  {
    const u16* qp = Qb + ((size_t)bh * SEQ_N + rowb + l31) * HEAD_DIM + hi * 8;
    #pragma unroll
    for (int db = 0; db < 4; db++) bq[db] = *(const bf16x8*)(qp + db * 16);
  }

  f32x16 o0, o1, od;                      // O d 0..31 / 32..63 / denominator
  #pragma unroll
  for (int r = 0; r < 16; r++) { o0[r] = 0.f; o1[r] = 0.f; od[r] = 0.f; }
  f32x16 zc;                              // loop-invariant zero C operand
  #pragma unroll
  for (int r = 0; r < 16; r++) zc[r] = 0.f;
  union { u32 u[4]; bf16x8 v; } ones;     // constant bf16 1.0 B frag
  ones.u[0] = ones.u[1] = ones.u[2] = ones.u[3] = 0x3F803F80u;

  const int krow0 = tid >> 3;                      // 0..31 (K shot row)
  const int ksg   = (tid & 7) ^ (krow0 & 7);       // pre-swizzled K src granule
  const int vrow0 = tid >> 4;                      // 0..15 (V shot d-row)
  const int vsg   = (tid & 15) ^ vrow0;            // pre-swizzled V src granule
  const u16* kg = Kb  + (size_t)bh * SEQ_K * HEAD_DIM;   // [k][d]
  const u16* vg = Vtb + (size_t)bh * HEAD_DIM * SEQ_K;   // [d][k]

#define STAGE(kt_, nb_) do {                                                   \
    _Pragma("unroll")                                                          \
    for (int s = 0; s < 4; s++) {                                              \
      async16(kg + (size_t)((kt_) + s * 32 + krow0) * HEAD_DIM + ksg * 8,      \
              &Ks[nb_][s * 2048 + tid * 8]);                                   \
      async16(vg + (size_t)(s * 16 + vrow0) * SEQ_K + (kt_) + vsg * 8,         \
              &Vs[nb_][s * 2048 + tid * 8]);                                   \
    }                                                                          \
  } while (0)

  STAGE(0, 0);
  __syncthreads();   // implicit vmcnt(0) drains the DMA

  for (int kt = 0; kt < SEQ_K; kt += 128) {
    const int cur = (kt >> 7) & 1;
    if (kt + 128 < SEQ_K) STAGE(kt + 128, cur ^ 1);  // lands under this iter
    const char* KsB = (const char*)Ks[cur];
    const char* VsB = (const char*)Vs[cur];

    #pragma unroll
    for (int g = 0; g < 4; g++) {
      // ---- S^T = K·Q^T: first MFMA consumes zc (no per-iter zero-init) ----
      __builtin_amdgcn_s_setprio(1);
      bf16x8 ka = *(const bf16x8*)(KsB + (g * 32 + l31) * 128 + (hi16 ^ swzK));
      f32x16 s = __builtin_amdgcn_mfma_f32_32x32x16_bf16(ka, bq[0], zc, 0, 0, 0);
      #pragma unroll
      for (int db = 1; db < 4; db++) {
        ka = *(const bf16x8*)(KsB + (g * 32 + l31) * 128 + ((db * 32 + hi16) ^ swzK));
        s = __builtin_amdgcn_mfma_f32_32x32x16_bf16(ka, bq[db], s, 0, 0, 0);
      }
      __builtin_amdgcn_s_setprio(0);

      // ---- exp2 + pack to bf16 PV A-frags (T12); denom via ones-MFMA ----
      float p[16];
      #pragma unroll
      for (int r = 0; r < 16; r++) p[r] = EXP2(s[r]);
      u32 w0 = pack2(p[0],  p[1]),  w1 = pack2(p[2],  p[3]);
      u32 w2 = pack2(p[4],  p[5]),  w3 = pack2(p[6],  p[7]);
      u32 w4 = pack2(p[8],  p[9]),  w5 = pack2(p[10], p[11]);
      u32 w6 = pack2(p[12], p[13]), w7 = pack2(p[14], p[15]);
      plswap(w0, w2); plswap(w1, w3);   // kslot 0: keys hi*8 + 0..7
      plswap(w4, w6); plswap(w5, w7);   // kslot 1: keys 16 + hi*8 + 0..7
      union PU { u32 u[4]; bf16x8 v; } pa0, pa1;
      pa0.u[0] = w0; pa0.u[1] = w1; pa0.u[2] = w2; pa0.u[3] = w3;
      pa1.u[0] = w4; pa1.u[1] = w5; pa1.u[2] = w6; pa1.u[3] = w7;

      // ---- O += P·V and od += P·1, alternating accumulators ----
      __builtin_amdgcn_s_setprio(1);
      bf16x8 vb00 = *(const bf16x8*)(VsB + (l31)*256      + ((g * 64 + hi16)      ^ swzV));
      bf16x8 vb01 = *(const bf16x8*)(VsB + (l31)*256      + ((g * 64 + 32 + hi16) ^ swzV));
      bf16x8 vb10 = *(const bf16x8*)(VsB + (32 + l31)*256 + ((g * 64 + hi16)      ^ swzV));
      bf16x8 vb11 = *(const bf16x8*)(VsB + (32 + l31)*256 + ((g * 64 + 32 + hi16) ^ swzV));
      o0 = __builtin_amdgcn_mfma_f32_32x32x16_bf16(pa0.v, vb00, o0, 0, 0, 0);
      o1 = __builtin_amdgcn_mfma_f32_32x32x16_bf16(pa0.v, vb10, o1, 0, 0, 0);
      od = __builtin_amdgcn_mfma_f32_32x32x16_bf16(pa0.v, ones.v, od, 0, 0, 0);
      o0 = __builtin_amdgcn_mfma_f32_32x32x16_bf16(pa1.v, vb01, o0, 0, 0, 0);
      o1 = __builtin_amdgcn_mfma_f32_32x32x16_bf16(pa1.v, vb11, o1, 0, 0, 0);
      od = __builtin_amdgcn_mfma_f32_32x32x16_bf16(pa1.v, ones.v, od, 0, 0, 0);
      __builtin_amdgcn_s_setprio(0);
    }
    __syncthreads();  // closes reads of cur + drains DMA into cur^1
  }
#undef STAGE

  // od[r] = full softmax denominator of q-row crow(r,hi) (all cols equal)
  const int bb = bh >> 4, hh = bh & 15;
  #pragma unroll
  for (int r = 0; r < 16; r++) {
    const int qrow = (r & 3) + 8 * (r >> 2) + 4 * hi;   // C-row of reg r
    const float invr = RCP(od[r]);
    const int gm = rowb + qrow;
    u16* op = Ob + ((size_t)bb * SEQ_N + gm) * EMB + hh * HEAD_DIM + l31;
    op[0]  = f2bf(o0[r] * invr);
    op[32] = f2bf(o1[r] * invr);
  }
}

extern "C" void kernel_launch(void* const* d_in, const int* in_sizes, int n_in,
                              void* d_out, int out_size, void* d_ws, size_t ws_size,
                              hipStream_t stream)
{
  const float* x     = (const float*)d_in[0];
  const float* ctx   = (const float*)d_in[1];
  const float* Wq    = (const float*)d_in[2];
  const float* bq    = (const float*)d_in[3];
  const float* Wkv   = (const float*)d_in[4];
  const float* bkv   = (const float*)d_in[5];
  const float* Wproj = (const float*)d_in[6];
  const float* bproj = (const float*)d_in[7];
  float* out = (float*)d_out;

  char* ws = (char*)d_ws;
  size_t off = 0;
  auto walloc = [&](size_t bytes) -> void* {
    void* p = ws + off;
    off += (bytes + 255) & ~(size_t)255;
    return p;
  };
  u16* xb   = (u16*)walloc((size_t)MROWS * EMB * 2);
  u16* cb   = (u16*)walloc((size_t)MROWS * EMB * 2);
  u16* Wqt  = (u16*)walloc((size_t)EMB * EMB * 2);
  u16* Wkvt = (u16*)walloc((size_t)2 * EMB * EMB * 2);
  u16* Wpt  = (u16*)walloc((size_t)EMB * EMB * 2);
  u16* Qb   = (u16*)walloc((size_t)MROWS * EMB * 2);
  u16* Kb   = (u16*)walloc((size_t)MROWS * EMB * 2);
  u16* Vtb  = (u16*)walloc((size_t)MROWS * EMB * 2);
  u16* Ob   = (u16*)walloc((size_t)MROWS * EMB * 2);

  cvt_all<<<12288, 256, 0, stream>>>(x, ctx, Wq, Wkv, Wproj, xb, cb, Wqt, Wkvt, Wpt);
  gemm_qkv<<<dim3(32, 24), 256, 0, stream>>>(xb, cb, Wqt, Wkvt, bq, bkv, Qb, Kb, Vtb);
  attn_kernel<<<dim3(32, 16), 256, 0, stream>>>(Qb, Kb, Vtb, Ob);
  gemm_proj<<<dim3(32, 8), 256, 0, stream>>>(Ob, Wpt, bproj, out);
}

// Round 10
// 201.845 us; speedup vs baseline: 1.0880x; 1.0013x over previous
//
#include <hip/hip_runtime.h>
#include <hip/hip_bf16.h>

typedef __attribute__((ext_vector_type(8))) short bf16x8;
typedef __attribute__((ext_vector_type(4))) float f32x4;
typedef __attribute__((ext_vector_type(16))) float f32x16;
typedef unsigned short u16;
typedef unsigned int u32;

#define NUM_HEAD 16
#define HEAD_DIM 64
#define SEQ_N 2048
#define SEQ_K 2048
#define EMB 1024
#define MROWS 4096          // B*N == B*K
// HEAD_DIM^-0.5 * log2(e): Q pre-scaled so softmax uses raw v_exp_f32 (exp2)
static constexpr float ATTN_SCALE_LOG2E = 0.125f * 1.44269504f;

#if __has_builtin(__builtin_amdgcn_exp2f)
#define EXP2(x) __builtin_amdgcn_exp2f(x)
#else
#define EXP2(x) __expf(0.69314718056f * (x))
#endif

#if __has_builtin(__builtin_amdgcn_rcpf)
#define RCP(x) __builtin_amdgcn_rcpf(x)
#else
#define RCP(x) (1.0f / (x))
#endif

__device__ __forceinline__ u16 f2bf(float f) {
  __hip_bfloat16 h = __float2bfloat16(f);
  return *reinterpret_cast<u16*>(&h);
}

__device__ __forceinline__ u32 pack2(float lo, float hi) {
  __hip_bfloat162 h = __float22bfloat162_rn(make_float2(lo, hi));
  return *reinterpret_cast<u32*>(&h);
}

// v_permlane32_swap_b32: a' = [a.lo | b.lo], b' = [a.hi | b.hi]
__device__ __forceinline__ void plswap(u32& a, u32& b) {
  auto r = __builtin_amdgcn_permlane32_swap(a, b, false, false);
  a = r[0]; b = r[1];
}

// async global->LDS 16B copy; LDS dest is wave-uniform base + lane*16 —
// staging layouts below are linear in tid; swizzles via pre-swizzled SOURCE.
__device__ __forceinline__ void async16(const u16* g, u16* l) {
  __builtin_amdgcn_global_load_lds(
      (const __attribute__((address_space(1))) unsigned int*)g,
      (__attribute__((address_space(3))) unsigned int*)l, 16, 0, 0);
}

// ---- fused input-convert + weight-transpose (one dispatch, R8) ------------
__global__ __launch_bounds__(256) void cvt_all(
    const float* __restrict__ x, const float* __restrict__ ctx,
    const float* __restrict__ Wq, const float* __restrict__ Wkv,
    const float* __restrict__ Wproj,
    u16* __restrict__ xb, u16* __restrict__ cb,
    u16* __restrict__ Wqt, u16* __restrict__ Wkvt, u16* __restrict__ Wpt) {
  __shared__ float tile[32][33];
  const int bid = blockIdx.x;
  if (bid < 8192) {
    const int n4 = MROWS * EMB / 4;
    int gid = bid * 256 + threadIdx.x;
    const float4* s; ushort4* d; int i;
    if (gid < n4) { s = (const float4*)x;   d = (ushort4*)xb; i = gid; }
    else          { s = (const float4*)ctx; d = (ushort4*)cb; i = gid - n4; }
    float4 v = s[i];
    ushort4 o;
    o.x = f2bf(v.x); o.y = f2bf(v.y); o.z = f2bf(v.z); o.w = f2bf(v.w);
    d[i] = o;
    return;
  }
  const int tb = bid - 8192;            // 0..4095
  const int z = tb >> 10;
  const float* W; u16* Wt; int srcN, colbase;
  if (z == 0)      { W = Wq;    Wt = Wqt;                          srcN = 1024; colbase = 0; }
  else if (z == 1) { W = Wkv;   Wt = Wkvt;                         srcN = 2048; colbase = 0; }
  else if (z == 2) { W = Wkv;   Wt = Wkvt + (size_t)1024 * 1024;   srcN = 2048; colbase = 1024; }
  else             { W = Wproj; Wt = Wpt;                          srcN = 1024; colbase = 0; }
  int n0 = (tb & 31) * 32, k0 = ((tb >> 5) & 31) * 32;
  int tx = threadIdx.x & 31, ty = threadIdx.x >> 5;
  #pragma unroll
  for (int i = ty; i < 32; i += 8)
    tile[i][tx] = W[(size_t)(k0 + i) * srcN + colbase + n0 + tx];
  __syncthreads();
  #pragma unroll
  for (int i = ty; i < 32; i += 8)
    Wt[(size_t)(n0 + i) * 1024 + k0 + tx] = f2bf(tile[tx][i]);
}

// ---------- fused Q + KV projection GEMM: m97-structure 128x128 (R5) -------
__global__ __launch_bounds__(256, 3) void gemm_qkv(
    const u16* __restrict__ xb, const u16* __restrict__ cb,
    const u16* __restrict__ Wqt, const u16* __restrict__ Wkvt,
    const float* __restrict__ bq, const float* __restrict__ bkv,
    u16* __restrict__ Qb, u16* __restrict__ Kb, u16* __restrict__ Vtb)
{
  __shared__ alignas(16) u16 smem[(128 + 128) * 64];
  u16* As = smem;                   // 128 x 64
  u16* Bs = smem + 128 * 64;        // 128 x 64
  const int tid = threadIdx.x;
  const bool isQ = (blockIdx.y < 8);
  const int n0 = (isQ ? blockIdx.y : blockIdx.y - 8) * 128;
  const int m0 = blockIdx.x * 128;
  const u16* A      = isQ ? xb : cb;
  const u16* Wt     = isQ ? Wqt : Wkvt;
  const float* bias = isQ ? bq : bkv;
  const int wave = tid >> 6, lane = tid & 63;
  const int wm = (wave >> 1) * 64, wn = (wave & 1) * 64;
  const int l15 = lane & 15, quad = lane >> 4;

  f32x4 acc[4][4];
  #pragma unroll
  for (int i = 0; i < 4; i++)
    #pragma unroll
    for (int j = 0; j < 4; j++)
      #pragma unroll
      for (int r = 0; r < 4; r++) acc[i][j][r] = 0.0f;

  const int srow = tid >> 3;          // 0..31
  const int scol = (tid & 7) * 8;     // u16 col
  const u16* ag = A + (size_t)(m0 + srow) * EMB + scol;
  const u16* bg = Wt + (size_t)(n0 + srow) * EMB + scol;
  const int ldsoff = tid * 8;

  for (int kt = 0; kt < EMB; kt += 64) {
    #pragma unroll
    for (int s = 0; s < 4; s++) {
      async16(ag + (size_t)(s * 32) * EMB + kt, &As[ldsoff + s * 2048]);
      async16(bg + (size_t)(s * 32) * EMB + kt, &Bs[ldsoff + s * 2048]);
    }
    __syncthreads();
    #pragma unroll
    for (int ks = 0; ks < 2; ks++) {
      bf16x8 af[4], bfr[4];
      #pragma unroll
      for (int i = 0; i < 4; i++)
        af[i]  = *(const bf16x8*)&As[(wm + i * 16 + l15) * 64 + ks * 32 + quad * 8];
      #pragma unroll
      for (int j = 0; j < 4; j++)
        bfr[j] = *(const bf16x8*)&Bs[(wn + j * 16 + l15) * 64 + ks * 32 + quad * 8];
      #pragma unroll
      for (int i = 0; i < 4; i++)
        #pragma unroll
        for (int j = 0; j < 4; j++)
          acc[i][j] = __builtin_amdgcn_mfma_f32_16x16x32_bf16(af[i], bfr[j], acc[i][j], 0, 0, 0);
    }
    __syncthreads();
  }

  const int h = ((n0 + wn) >> 6) & 15;      // wave-uniform head
  if (isQ) {
    #pragma unroll
    for (int j = 0; j < 4; j++) {
      const int gc = n0 + wn + j * 16 + l15;
      const float bv = bias[gc];
      const int d = j * 16 + l15;
      #pragma unroll
      for (int i = 0; i < 4; i++) {
        #pragma unroll
        for (int r = 0; r < 4; r++) {
          const int gm = m0 + wm + i * 16 + quad * 4 + r;
          const int bb = gm >> 11, nn = gm & 2047;
          Qb[((size_t)(bb * NUM_HEAD + h) * SEQ_N + nn) * HEAD_DIM + d] =
              f2bf((acc[i][j][r] + bv) * ATTN_SCALE_LOG2E);
        }
      }
    }
  } else if ((n0 >> 10) == 0) {  // K half -> [B,H,K,hd]
    #pragma unroll
    for (int j = 0; j < 4; j++) {
      const int gc = n0 + wn + j * 16 + l15;
      const float bv = bias[gc];
      const int d = j * 16 + l15;
      #pragma unroll
      for (int i = 0; i < 4; i++) {
        #pragma unroll
        for (int r = 0; r < 4; r++) {
          const int gm = m0 + wm + i * 16 + quad * 4 + r;
          const int bb = gm >> 11, kk = gm & 2047;
          Kb[((size_t)(bb * NUM_HEAD + h) * SEQ_K + kk) * HEAD_DIM + d] =
              f2bf(acc[i][j][r] + bv);
        }
      }
    }
  } else {  // V half -> [B,H,hd,K], barrier-free per-wave LDS transpose
    u16* wbuf = smem + wave * 1088;     // 16 x 68 u16, wave-private
    const int gm0 = m0 + wm;
    const int bb = gm0 >> 11;
    const int kk0 = gm0 & 2047;
    #pragma unroll
    for (int j = 0; j < 4; j++) {
      const int gc = n0 + wn + j * 16 + l15;
      const float bv = bias[gc];
      #pragma unroll
      for (int i = 0; i < 4; i++) {
        ushort4 pk;
        pk.x = f2bf(acc[i][j][0] + bv);
        pk.y = f2bf(acc[i][j][1] + bv);
        pk.z = f2bf(acc[i][j][2] + bv);
        pk.w = f2bf(acc[i][j][3] + bv);
        *(ushort4*)&wbuf[l15 * 68 + i * 16 + quad * 4] = pk;
      }
      #pragma unroll
      for (int it = 0; it < 2; it++) {
        const int dd = it * 8 + (lane >> 3);
        const int kp = (lane & 7) * 8;
        uint4 v = *(const uint4*)&wbuf[dd * 68 + kp];
        *(uint4*)(Vtb + ((size_t)(bb * NUM_HEAD + h) * HEAD_DIM + j * 16 + dd) * SEQ_K
                  + kk0 + kp) = v;
      }
    }
  }
}

// ---------- out-projection GEMM: m97-structure 128x128 (R9) ----------------
__global__ __launch_bounds__(256, 3) void gemm_proj(
    const u16* __restrict__ A, const u16* __restrict__ Wt,
    const float* __restrict__ bias, float* __restrict__ outF)
{
  __shared__ alignas(16) u16 smem[(128 + 128) * 64];
  u16* As = smem;                   // 128 x 64
  u16* Bs = smem + 128 * 64;        // 128 x 64
  const int tid = threadIdx.x;
  const int n0 = blockIdx.y * 128, m0 = blockIdx.x * 128;
  const int wave = tid >> 6, lane = tid & 63;
  const int wm = (wave >> 1) * 64, wn = (wave & 1) * 64;
  const int l15 = lane & 15, quad = lane >> 4;

  f32x4 acc[4][4];
  #pragma unroll
  for (int i = 0; i < 4; i++)
    #pragma unroll
    for (int j = 0; j < 4; j++)
      #pragma unroll
      for (int r = 0; r < 4; r++) acc[i][j][r] = 0.0f;

  const int srow = tid >> 3;          // 0..31
  const int scol = (tid & 7) * 8;     // u16 col
  const u16* ag = A + (size_t)(m0 + srow) * EMB + scol;
  const u16* bg = Wt + (size_t)(n0 + srow) * EMB + scol;
  const int ldsoff = tid * 8;

  for (int kt = 0; kt < EMB; kt += 64) {
    #pragma unroll
    for (int s = 0; s < 4; s++) {
      async16(ag + (size_t)(s * 32) * EMB + kt, &As[ldsoff + s * 2048]);
      async16(bg + (size_t)(s * 32) * EMB + kt, &Bs[ldsoff + s * 2048]);
    }
    __syncthreads();
    #pragma unroll
    for (int ks = 0; ks < 2; ks++) {
      bf16x8 af[4], bfr[4];
      #pragma unroll
      for (int i = 0; i < 4; i++)
        af[i]  = *(const bf16x8*)&As[(wm + i * 16 + l15) * 64 + ks * 32 + quad * 8];
      #pragma unroll
      for (int j = 0; j < 4; j++)
        bfr[j] = *(const bf16x8*)&Bs[(wn + j * 16 + l15) * 64 + ks * 32 + quad * 8];
      #pragma unroll
      for (int i = 0; i < 4; i++)
        #pragma unroll
        for (int j = 0; j < 4; j++)
          acc[i][j] = __builtin_amdgcn_mfma_f32_16x16x32_bf16(af[i], bfr[j], acc[i][j], 0, 0, 0);
    }
    __syncthreads();
  }

  #pragma unroll
  for (int j = 0; j < 4; j++) {
    const int gc = n0 + wn + j * 16 + l15;
    const float bv = bias[gc];
    #pragma unroll
    for (int i = 0; i < 4; i++) {
      #pragma unroll
      for (int r = 0; r < 4; r++) {
        const int gm = m0 + wm + i * 16 + quad * 4 + r;
        outF[(size_t)gm * EMB + gc] = acc[i][j][r] + bv;
      }
    }
  }
}

// ------- flash attention R10: asm-fenced 4-chain QK interleave ----------------
// R4-R9 falsified issue-mix / SGB-ILP / occupancy / split-K; VGPR=88 of a
// free 256 budget proves hipcc kept serializing the group chains.  R10:
// phase A computes ALL 4 groups' QK db-outer — 4 independent MFMA chains,
// each instruction issuing while its chain-predecessor is 4 issues back —
// pinned by empty asm register-touches on sg[g] between db-rounds (true
// dataflow edges; cannot be re-clustered, unlike R7's sched_group_barrier).
// With all 4 S-tiles live at once (64 VGPR), softmax(g+1) overlaps PV(g)
// naturally.  LDS still caps occupancy at 2 blocks/CU, so VGPR<=256 is free.
// Kept: 4 waves x 32 q-rows, KT=128 dbuf DMA, XOR swizzles, zero-C hoist,
// ones-column MFMA denominator, bf16 out.
__global__ __launch_bounds__(256, 2) void attn_kernel(
    const u16* __restrict__ Qb, const u16* __restrict__ Kb,
    const u16* __restrict__ Vtb, u16* __restrict__ Ob)
{
  __shared__ alignas(16) u16 Ks[2][128 * 64];   // [key][d], pitch 128B, 3-bit swz
  __shared__ alignas(16) u16 Vs[2][64 * 128];   // [d][key], pitch 256B, 4-bit swz
  const int tid = threadIdx.x;
  const int bh = blockIdx.x;
  const int m0 = blockIdx.y * 128;
  const int wave = tid >> 6, lane = tid & 63;
  const int l31 = lane & 31, hi = lane >> 5;
  const int hi16 = hi * 16;
  const int swzK = (l31 & 7) << 4;        // K read-side XOR (row&7 == l31&7)
  const int swzV = (l31 & 15) << 4;       // V read-side XOR (d&15 == l31&15)
  const int rowb = m0 + wave * 32;

  bf16x8 bq[4];
  {
    const u16* qp = Qb + ((size_t)bh * SEQ_N + rowb + l31) * HEAD_DIM + hi * 8;
    #pragma unroll
    for (int db = 0; db < 4; db++) bq[db] = *(const bf16x8*)(qp + db * 16);
  }

  f32x16 o0, o1, od;                      // O d 0..31 / 32..63 / denominator
  #pragma unroll
  for (int r = 0; r < 16; r++) { o0[r] = 0.f; o1[r] = 0.f; od[r] = 0.f; }
  f32x16 zc;                              // loop-invariant zero C operand
  #pragma unroll
  for (int r = 0; r < 16; r++) zc[r] = 0.f;
  union { u32 u[4]; bf16x8 v; } ones;     // constant bf16 1.0 B frag
  ones.u[0] = ones.u[1] = ones.u[2] = ones.u[3] = 0x3F803F80u;

  const int krow0 = tid >> 3;                      // 0..31 (K shot row)
  const int ksg   = (tid & 7) ^ (krow0 & 7);       // pre-swizzled K src granule
  const int vrow0 = tid >> 4;                      // 0..15 (V shot d-row)
  const int vsg   = (tid & 15) ^ vrow0;            // pre-swizzled V src granule
  const u16* kg = Kb  + (size_t)bh * SEQ_K * HEAD_DIM;   // [k][d]
  const u16* vg = Vtb + (size_t)bh * HEAD_DIM * SEQ_K;   // [d][k]

#define STAGE(kt_, nb_) do {                                                   \
    _Pragma("unroll")                                                          \
    for (int s = 0; s < 4; s++) {                                              \
      async16(kg + (size_t)((kt_) + s * 32 + krow0) * HEAD_DIM + ksg * 8,      \
              &Ks[nb_][s * 2048 + tid * 8]);                                   \
      async16(vg + (size_t)(s * 16 + vrow0) * SEQ_K + (kt_) + vsg * 8,         \
              &Vs[nb_][s * 2048 + tid * 8]);                                   \
    }                                                                          \
  } while (0)

  STAGE(0, 0);
  __syncthreads();   // implicit vmcnt(0) drains the DMA

  for (int kt = 0; kt < SEQ_K; kt += 128) {
    const int cur = (kt >> 7) & 1;
    if (kt + 128 < SEQ_K) STAGE(kt + 128, cur ^ 1);  // lands under this iter
    const char* KsB = (const char*)Ks[cur];
    const char* VsB = (const char*)Vs[cur];

    // ---- phase A: 4 independent QK chains, db-outer, asm-fenced rounds ----
    f32x16 sg[4];
    #pragma unroll
    for (int db = 0; db < 4; db++) {
      bf16x8 ka[4];
      #pragma unroll
      for (int g = 0; g < 4; g++)
        ka[g] = *(const bf16x8*)(KsB + (g * 32 + l31) * 128 + ((db * 32 + hi16) ^ swzK));
      if (db == 0) {
        #pragma unroll
        for (int g = 0; g < 4; g++)
          sg[g] = __builtin_amdgcn_mfma_f32_32x32x16_bf16(ka[g], bq[0], zc, 0, 0, 0);
      } else {
        #pragma unroll
        for (int g = 0; g < 4; g++)
          sg[g] = __builtin_amdgcn_mfma_f32_32x32x16_bf16(ka[g], bq[db], sg[g], 0, 0, 0);
      }
      // true dataflow fence: orders round db before db+1 for ALL 4 chains,
      // forcing the g0..g3 interleave (chain latency hidden by 4-way issue)
      asm volatile("" : "+v"(sg[0][0]), "+v"(sg[1][0]), "+v"(sg[2][0]), "+v"(sg[3][0]));
    }

    // ---- phase B: per group softmax+pack then PV; all sg live so the
    // scheduler can run exp/pack of g+1 under PV MFMAs of g ----
    #pragma unroll
    for (int g = 0; g < 4; g++) {
      float p[16];
      #pragma unroll
      for (int r = 0; r < 16; r++) p[r] = EXP2(sg[g][r]);
      u32 w0 = pack2(p[0],  p[1]),  w1 = pack2(p[2],  p[3]);
      u32 w2 = pack2(p[4],  p[5]),  w3 = pack2(p[6],  p[7]);
      u32 w4 = pack2(p[8],  p[9]),  w5 = pack2(p[10], p[11]);
      u32 w6 = pack2(p[12], p[13]), w7 = pack2(p[14], p[15]);
      plswap(w0, w2); plswap(w1, w3);   // kslot 0: keys hi*8 + 0..7
      plswap(w4, w6); plswap(w5, w7);   // kslot 1: keys 16 + hi*8 + 0..7
      union PU { u32 u[4]; bf16x8 v; } pa0, pa1;
      pa0.u[0] = w0; pa0.u[1] = w1; pa0.u[2] = w2; pa0.u[3] = w3;
      pa1.u[0] = w4; pa1.u[1] = w5; pa1.u[2] = w6; pa1.u[3] = w7;

      bf16x8 vb00 = *(const bf16x8*)(VsB + (l31)*256      + ((g * 64 + hi16)      ^ swzV));
      bf16x8 vb01 = *(const bf16x8*)(VsB + (l31)*256      + ((g * 64 + 32 + hi16) ^ swzV));
      bf16x8 vb10 = *(const bf16x8*)(VsB + (32 + l31)*256 + ((g * 64 + hi16)      ^ swzV));
      bf16x8 vb11 = *(const bf16x8*)(VsB + (32 + l31)*256 + ((g * 64 + 32 + hi16) ^ swzV));
      o0 = __builtin_amdgcn_mfma_f32_32x32x16_bf16(pa0.v, vb00, o0, 0, 0, 0);
      o1 = __builtin_amdgcn_mfma_f32_32x32x16_bf16(pa0.v, vb10, o1, 0, 0, 0);
      od = __builtin_amdgcn_mfma_f32_32x32x16_bf16(pa0.v, ones.v, od, 0, 0, 0);
      o0 = __builtin_amdgcn_mfma_f32_32x32x16_bf16(pa1.v, vb01, o0, 0, 0, 0);
      o1 = __builtin_amdgcn_mfma_f32_32x32x16_bf16(pa1.v, vb11, o1, 0, 0, 0);
      od = __builtin_amdgcn_mfma_f32_32x32x16_bf16(pa1.v, ones.v, od, 0, 0, 0);
    }
    __syncthreads();  // closes reads of cur + drains DMA into cur^1
  }
#undef STAGE

  // od[r] = full softmax denominator of q-row crow(r,hi) (all cols equal)
  const int bb = bh >> 4, hh = bh & 15;
  #pragma unroll
  for (int r = 0; r < 16; r++) {
    const int qrow = (r & 3) + 8 * (r >> 2) + 4 * hi;   // C-row of reg r
    const float invr = RCP(od[r]);
    const int gm = rowb + qrow;
    u16* op = Ob + ((size_t)bb * SEQ_N + gm) * EMB + hh * HEAD_DIM + l31;
    op[0]  = f2bf(o0[r] * invr);
    op[32] = f2bf(o1[r] * invr);
  }
}

extern "C" void kernel_launch(void* const* d_in, const int* in_sizes, int n_in,
                              void* d_out, int out_size, void* d_ws, size_t ws_size,
                              hipStream_t stream)
{
  const float* x     = (const float*)d_in[0];
  const float* ctx   = (const float*)d_in[1];
  const float* Wq    = (const float*)d_in[2];
  const float* bq    = (const float*)d_in[3];
  const float* Wkv   = (const float*)d_in[4];
  const float* bkv   = (const float*)d_in[5];
  const float* Wproj = (const float*)d_in[6];
  const float* bproj = (const float*)d_in[7];
  float* out = (float*)d_out;

  char* ws = (char*)d_ws;
  size_t off = 0;
  auto walloc = [&](size_t bytes) -> void* {
    void* p = ws + off;
    off += (bytes + 255) & ~(size_t)255;
    return p;
  };
  u16* xb   = (u16*)walloc((size_t)MROWS * EMB * 2);
  u16* cb   = (u16*)walloc((size_t)MROWS * EMB * 2);
  u16* Wqt  = (u16*)walloc((size_t)EMB * EMB * 2);
  u16* Wkvt = (u16*)walloc((size_t)2 * EMB * EMB * 2);
  u16* Wpt  = (u16*)walloc((size_t)EMB * EMB * 2);
  u16* Qb   = (u16*)walloc((size_t)MROWS * EMB * 2);
  u16* Kb   = (u16*)walloc((size_t)MROWS * EMB * 2);
  u16* Vtb  = (u16*)walloc((size_t)MROWS * EMB * 2);
  u16* Ob   = (u16*)walloc((size_t)MROWS * EMB * 2);

  cvt_all<<<12288, 256, 0, stream>>>(x, ctx, Wq, Wkv, Wproj, xb, cb, Wqt, Wkvt, Wpt);
  gemm_qkv<<<dim3(32, 24), 256, 0, stream>>>(xb, cb, Wqt, Wkvt, bq, bkv, Qb, Kb, Vtb);
  attn_kernel<<<dim3(32, 16), 256, 0, stream>>>(Qb, Kb, Vtb, Ob);
  gemm_proj<<<dim3(32, 8), 256, 0, stream>>>(Ob, Wpt, bproj, out);
}